// Round 3
// baseline (1902.972 us; speedup 1.0000x reference)
//
#include <hip/hip_runtime.h>
#include <hip/hip_bf16.h>
#include <math.h>

using bf16 = __hip_bfloat16;
typedef __attribute__((ext_vector_type(8))) short s8v;
typedef __attribute__((ext_vector_type(4))) float f4v;

#define MTOT 65536   // B*T
#define TLEN 2048
#define NCHUNK 16
#define TCH 128

__device__ __forceinline__ float b2f(bf16 x) { return __bfloat162float(x); }
__device__ __forceinline__ bf16 f2b(float x) { return __float2bfloat16(x); }

// flagged load: f32 buffer if f!=0 else bf16 buffer
__device__ __forceinline__ float ldf(const void* p, size_t i, int f) {
    return f ? ((const float*)p)[i] : b2f(((const bf16*)p)[i]);
}

__device__ __forceinline__ void ld_g2l(const void* g, void* l) {
    __builtin_amdgcn_global_load_lds(
        (const __attribute__((address_space(1))) void*)g,
        (__attribute__((address_space(3))) void*)l,
        16, 0, 0);
}

// ---------------- dtype detection ----------------
// x ~ N(0,1): genuine bf16 never has exponent field 0x00/0xFF; f32 data
// read as bf16 halves hits those ~1.5% of the time.
__global__ void detect_k(const unsigned short* __restrict__ x, int* __restrict__ flag) {
    int tid = threadIdx.x;
    int cnt = 0;
    for (int i = tid; i < 8192; i += 256) {
        int e = (x[i] >> 7) & 0xFF;
        if (e == 0 || e == 0xFF) cnt++;
    }
    __shared__ int red[256];
    red[tid] = cnt;
    __syncthreads();
    for (int s = 128; s > 0; s >>= 1) {
        if (tid < s) red[tid] += red[tid + s];
        __syncthreads();
    }
    if (tid == 0) flag[0] = (red[0] >= 2) ? 1 : 0;
}

// generic convert-to-bf16
__global__ void cvt_k(const void* __restrict__ src, bf16* __restrict__ dst, int n,
                      const int* __restrict__ flag) {
    int f = *flag;
    int i = blockIdx.x * 256 + threadIdx.x;
    if (i < n) dst[i] = f2b(ldf(src, i, f));
}

// lambda (fp32, no bf16 round-trip) + gamma tables for all 6 layers
__global__ void lamgam_k(const void* __restrict__ nu, const void* __restrict__ th,
                         float* __restrict__ lamb, float* __restrict__ gamt,
                         const int* __restrict__ flag) {
    int f = *flag;
    int g = blockIdx.x * 256 + threadIdx.x;  // 1536
    float nl = ldf(nu, g, f), tl = ldf(th, g, f);
    float mag = expf(-expf(nl));
    float ang = expf(tl);
    lamb[g * 2] = mag * cosf(ang);
    lamb[g * 2 + 1] = mag * sinf(ang);
    gamt[g] = sqrtf(fmaxf(1.f - mag * mag, 1e-12f));
}

// ---------------- GEMM: out[m,n] = sum_k A[m,k] * W[n,k] (+epilogue) -------
// A: [M, lda] bf16 row-major, W: [N, K] bf16 row-major (pre-transposed).
// grid = (M/128, N/128), block = 256. 128x128 tile, BK=64, 16x16x32 MFMA.
// EPI 0: plain bf16                     (Bu)
// EPI 1: +bias -> bf16 outB AND outB2  (encoder -> xc, y)
// EPI 2: +Dv[n]*aux[m,n] -> bf16       (LRU C-out; outB aliases aux, in-place safe)
// EPI 3: sigmoid(v+bias) -> bf16       (MLP gate)
// EPI 4: (v+bias)*aux[m,n] -> bf16     (MLP value*gate; outB aliases aux)
// EPI 5: v+bias+aux[m,n] -> bf16       (W2 + residual y -> xc)
template<int EPI>
__global__ __launch_bounds__(256)
void gemm_bt(const bf16* __restrict__ A, int lda,
             const bf16* __restrict__ W, int K,
             bf16* __restrict__ outB, bf16* __restrict__ outB2, int ldo,
             const bf16* __restrict__ bias,
             const bf16* __restrict__ Dv, const bf16* __restrict__ aux)
{
    const int bm = blockIdx.x, bn = blockIdx.y;
    const int tid = threadIdx.x;
    const int lane = tid & 63, wv = tid >> 6;
    const int wm = wv >> 1, wn = wv & 1;
    const int quad = lane >> 4, cl = lane & 15;

    __shared__ __align__(16) short As[128 * 64];
    __shared__ __align__(16) short Ws[128 * 64];

    f4v acc[4][4];
#pragma unroll
    for (int i = 0; i < 4; i++)
#pragma unroll
        for (int j = 0; j < 4; j++) acc[i][j] = (f4v){0.f, 0.f, 0.f, 0.f};

    const char* Abase = (const char*)(A + (size_t)bm * 128 * lda);
    const char* Wbase = (const char*)(W + (size_t)bn * 128 * K);
    const int rsub = lane >> 3;                       // 0..7
    const int swz = ((lane & 7) ^ rsub) * 16;         // XOR-swizzled granule byte

    for (int kt = 0; kt < K; kt += 64) {
#pragma unroll
        for (int p = 0; p < 4; ++p) {
            int seg = p * 4 + wv;                     // 0..15 (8 rows each)
            const char* ga = Abase + (size_t)(seg * 8 + rsub) * (lda * 2) + kt * 2 + swz;
            ld_g2l(ga, (char*)As + seg * 1024);
            const char* gw = Wbase + (size_t)(seg * 8 + rsub) * (K * 2) + kt * 2 + swz;
            ld_g2l(gw, (char*)Ws + seg * 1024);
        }
        __syncthreads();
#pragma unroll
        for (int kk = 0; kk < 2; ++kk) {
            s8v af[4], bfr[4];
#pragma unroll
            for (int i = 0; i < 4; i++) {
                int r = wm * 64 + i * 16 + cl;
                int poff = (((kk * 4 + quad) ^ (r & 7)) * 8);
                af[i] = *(const s8v*)&As[r * 64 + poff];
            }
#pragma unroll
            for (int j = 0; j < 4; j++) {
                int r = wn * 64 + j * 16 + cl;
                int poff = (((kk * 4 + quad) ^ (r & 7)) * 8);
                bfr[j] = *(const s8v*)&Ws[r * 64 + poff];
            }
#pragma unroll
            for (int i = 0; i < 4; i++)
#pragma unroll
                for (int j = 0; j < 4; j++)
                    acc[i][j] = __builtin_amdgcn_mfma_f32_16x16x32_bf16(af[i], bfr[j], acc[i][j], 0, 0, 0);
        }
        __syncthreads();
    }

    const size_t ld = (size_t)ldo;
#pragma unroll
    for (int i = 0; i < 4; i++) {
#pragma unroll
        for (int j = 0; j < 4; j++) {
#pragma unroll
            for (int r = 0; r < 4; r++) {
                int m = bm * 128 + wm * 64 + i * 16 + quad * 4 + r;
                int n = bn * 128 + wn * 64 + j * 16 + cl;
                size_t idx = (size_t)m * ld + n;
                float v = acc[i][j][r];
                if (EPI == 0) {
                    outB[idx] = f2b(v);
                } else if (EPI == 1) {
                    v += b2f(bias[n]);
                    outB[idx] = f2b(v);
                    outB2[idx] = f2b(v);
                } else if (EPI == 2) {
                    v += b2f(Dv[n]) * b2f(aux[idx]);
                    outB[idx] = f2b(v);
                } else if (EPI == 3) {
                    v += b2f(bias[n]);
                    outB[idx] = f2b(1.f / (1.f + expf(-v)));
                } else if (EPI == 4) {
                    v = (v + b2f(bias[n])) * b2f(aux[idx]);
                    outB[idx] = f2b(v);
                } else if (EPI == 5) {
                    v += b2f(bias[n]) + b2f(aux[idx]);
                    outB[idx] = f2b(v);
                }
            }
        }
    }
}

// ---------------- BatchNorm (two-pass, no atomics) ----------------
__global__ void bn_part(const bf16* __restrict__ x, float* __restrict__ part) {
    int e = threadIdx.x;
    size_t base = (size_t)blockIdx.x * 128;
    float s = 0.f, s2 = 0.f;
    for (int r = 0; r < 128; r++) {
        float v = b2f(x[(base + r) * 256 + e]);
        s += v; s2 += v * v;
    }
    part[(size_t)blockIdx.x * 256 + e] = s;
    part[131072 + (size_t)blockIdx.x * 256 + e] = s2;
}

__global__ void bn_finish(const float* __restrict__ part, float* __restrict__ stats) {
    int e = threadIdx.x;
    float s = 0.f, s2 = 0.f;
    for (int b = 0; b < 512; b++) {
        s += part[(size_t)b * 256 + e];
        s2 += part[131072 + (size_t)b * 256 + e];
    }
    float mu = s * (1.f / 65536.f);
    float var = s2 * (1.f / 65536.f) - mu * mu;
    stats[e] = mu;
    stats[256 + e] = rsqrtf(var + 1e-5f);
}

__global__ void bn_apply(const bf16* __restrict__ xc, const float* __restrict__ stats,
                         const bf16* __restrict__ sc, const bf16* __restrict__ bi,
                         bf16* __restrict__ out) {
    int e = threadIdx.x;
    float mu = stats[e];
    float is = stats[256 + e] * b2f(sc[e]);
    float bb = b2f(bi[e]);
    size_t m0 = (size_t)blockIdx.x * 4;
    for (int r = 0; r < 4; r++) {
        float v = b2f(xc[(m0 + r) * 256 + e]);
        out[(m0 + r) * 256 + e] = f2b((v - mu) * is + bb);
    }
}

// ---------------- LRU scan (chunked, in-place over Bu) ----------------
// bu layout: [M, 512] bf16, cols 0..255 = re, 256..511 = im
// lam: per-layer fp32 table [256][2]
__global__ void lru_carry(const bf16* __restrict__ bu, const float* __restrict__ lam,
                          float* __restrict__ carry) {
    int g = blockIdx.x * 256 + threadIdx.x;  // 131072 chains
    int h = g & 255, c = (g >> 8) & 15, b = g >> 12;
    float lr = lam[h * 2], li = lam[h * 2 + 1];
    float sr = 0.f, si = 0.f;
    const bf16* p = bu + ((size_t)(b * TLEN + c * TCH)) * 512 + h;
    for (int t = 0; t < TCH; t++) {
        float ur = b2f(p[0]), ui = b2f(p[256]);
        float nr = lr * sr - li * si + ur;
        si = lr * si + li * sr + ui;
        sr = nr;
        p += 512;
    }
    carry[(size_t)g * 2] = sr;
    carry[(size_t)g * 2 + 1] = si;
}

__global__ void lru_prefix(const float* __restrict__ carry, float* __restrict__ pre,
                           const float* __restrict__ lam) {
    int g = blockIdx.x * 256 + threadIdx.x;  // 8192
    int h = g & 255, b = g >> 8;
    float pr = lam[h * 2], pi = lam[h * 2 + 1];  // lam^128 via 7 squarings
    for (int k = 0; k < 7; k++) { float nr = pr * pr - pi * pi; pi = 2.f * pr * pi; pr = nr; }
    float er = 0.f, ei = 0.f;
    for (int c = 0; c < NCHUNK; c++) {
        size_t idx = ((size_t)(b * NCHUNK + c) * 256 + h) * 2;
        pre[idx] = er; pre[idx + 1] = ei;
        float cr = carry[idx], ci = carry[idx + 1];
        float nr = pr * er - pi * ei + cr;
        ei = pr * ei + pi * er + ci;
        er = nr;
    }
}

__global__ void lru_final(bf16* __restrict__ bu, const float* __restrict__ pre,
                          const float* __restrict__ lam) {
    int g = blockIdx.x * 256 + threadIdx.x;  // 131072
    int h = g & 255, c = (g >> 8) & 15, b = g >> 12;
    float lr = lam[h * 2], li = lam[h * 2 + 1];
    float sr = pre[(size_t)g * 2], si = pre[(size_t)g * 2 + 1];
    bf16* p = bu + ((size_t)(b * TLEN + c * TCH)) * 512 + h;
    for (int t = 0; t < TCH; t++) {
        float ur = b2f(p[0]), ui = b2f(p[256]);
        float nr = lr * sr - li * si + ur;
        si = lr * si + li * sr + ui;
        sr = nr;
        p[0] = f2b(sr);
        p[256] = f2b(si);
        p += 512;
    }
}

// ---------------- pooling + head ----------------
__global__ void pool_part(const bf16* __restrict__ xc, float* __restrict__ part) {
    int blk = blockIdx.x;  // 512
    int b = blk >> 4, tc = blk & 15;
    int e = threadIdx.x;
    const bf16* p = xc + ((size_t)b * TLEN + tc * TCH) * 256 + e;
    float s = 0.f;
    for (int r = 0; r < TCH; r++) { s += b2f(*p); p += 256; }
    part[(size_t)blk * 256 + e] = s;
}

__global__ void head_k(const float* __restrict__ part, const bf16* __restrict__ W_out,
                       const bf16* __restrict__ b_out, void* __restrict__ out,
                       const int* __restrict__ flag) {
    int b = blockIdx.x;
    int tid = threadIdx.x;
    __shared__ float sp[256];
    __shared__ float red[160];
    float s = 0.f;
    for (int c = 0; c < 16; c++) s += part[((size_t)(b * 16 + c)) * 256 + tid];
    sp[tid] = s * (1.f / 2048.f);
    __syncthreads();
    if (tid < 160) {
        int o = tid >> 4, sg = tid & 15;
        float a = 0.f;
        for (int e = sg; e < 256; e += 16) a += sp[e] * b2f(W_out[e * 10 + o]);
        red[tid] = a;
    }
    __syncthreads();
    if (tid < 10) {
        float acc = b2f(b_out[tid]);
        for (int sg = 0; sg < 16; sg++) acc += red[tid * 16 + sg];
        if (*flag) ((float*)out)[b * 10 + tid] = acc;
        else       ((bf16*)out)[b * 10 + tid] = f2b(acc);
    }
}

// ---------------- weight packing (flagged dtype reads) ----------------
__global__ void pack_wt_enc(const void* __restrict__ W_enc, bf16* __restrict__ out,
                            const int* __restrict__ flag) {
    int f = *flag;
    int g = blockIdx.x * 256 + threadIdx.x;  // 16384
    int n = g >> 6, k = g & 63;
    out[g] = f2b(ldf(W_enc, (size_t)k * 256 + n, f));
}

__global__ void pack_wb(const void* __restrict__ B_re, const void* __restrict__ B_im,
                        size_t off, const float* __restrict__ gam,
                        bf16* __restrict__ out, const int* __restrict__ flag) {
    int f = *flag;
    int g = blockIdx.x * 256 + threadIdx.x;  // 512*256
    int n = g >> 8, e = g & 255;
    int h = n & 255;
    const void* src = (n < 256) ? B_re : B_im;
    out[g] = f2b(ldf(src, off + (size_t)h * 256 + e, f) * gam[h]);
}

__global__ void pack_wc(const void* __restrict__ C_re, const void* __restrict__ C_im,
                        size_t off, bf16* __restrict__ out, const int* __restrict__ flag) {
    int f = *flag;
    int g = blockIdx.x * 256 + threadIdx.x;  // 256*512
    int e = g >> 9, k = g & 511;
    float v = (k < 256) ? ldf(C_re, off + (size_t)e * 256 + k, f)
                        : -ldf(C_im, off + (size_t)e * 256 + (k - 256), f);
    out[g] = f2b(v);
}

__global__ void pack_w1t(const void* __restrict__ W1, size_t off, bf16* __restrict__ out,
                         const int* __restrict__ flag) {
    int f = *flag;
    int g = blockIdx.x * 256 + threadIdx.x;  // 1024*256
    int n = g >> 8, k = g & 255;
    out[g] = f2b(ldf(W1, off + (size_t)k * 1024 + n, f));
}

__global__ void pack_w2t(const void* __restrict__ W2, size_t off, bf16* __restrict__ out,
                         const int* __restrict__ flag) {
    int f = *flag;
    int g = blockIdx.x * 256 + threadIdx.x;  // 256*512
    int n = g >> 9, k = g & 511;
    out[g] = f2b(ldf(W2, off + (size_t)k * 256 + n, f));
}

extern "C" void kernel_launch(void* const* d_in, const int* in_sizes, int n_in,
                              void* d_out, int out_size, void* d_ws, size_t ws_size,
                              hipStream_t stream) {
    (void)in_sizes; (void)n_in; (void)out_size; (void)ws_size;
    const void* x      = d_in[0];
    const void* W_enc  = d_in[1];
    const void* b_enc  = d_in[2];
    const void* nu_log = d_in[3];
    const void* th_log = d_in[4];
    const void* B_re   = d_in[5];
    const void* B_im   = d_in[6];
    const void* C_re   = d_in[7];
    const void* C_im   = d_in[8];
    const void* Dp     = d_in[9];
    const void* W1     = d_in[10];
    const void* b1     = d_in[11];
    const void* W2     = d_in[12];
    const void* b2     = d_in[13];
    const void* bn_s   = d_in[14];
    const void* bn_b   = d_in[15];
    const void* W_out  = d_in[16];
    const void* b_out  = d_in[17];

    // workspace layout (~173 MB)
    char* w = (char*)d_ws;
    bf16* xc  = (bf16*)w; w += (size_t)MTOT * 256 * 2;   // residual stream
    bf16* y   = (bf16*)w; w += (size_t)MTOT * 256 * 2;   // residual anchor
    bf16* hbn = (bf16*)w; w += (size_t)MTOT * 256 * 2;   // BN out / LRU out (in-place)
    bf16* bu  = (bf16*)w; w += (size_t)MTOT * 512 * 2;   // Bu/hs, then gate/GLU; head aliased by xb
    float* stats  = (float*)w; w += 4096;
    float* bnpart = (float*)w; w += 1048576;
    float* carry  = (float*)w; w += 1048576;
    float* pre    = (float*)w; w += 1048576;
    float* part   = (float*)w; w += 524288;
    float* lamb   = (float*)w; w += 12288;               // 1536*2 fp32
    float* gamt   = (float*)w; w += 6144;                // 1536 fp32
    int*   flag   = (int*)w;  w += 256;
    bf16* wt_enc = (bf16*)w; w += 32768;
    bf16* wb  = (bf16*)w; w += 262144;
    bf16* wc  = (bf16*)w; w += 262144;
    bf16* w1t = (bf16*)w; w += 524288;
    bf16* w2t = (bf16*)w; w += 262144;
    // small converted params (bf16)
    bf16* b_encb = (bf16*)w; w += 512;
    bf16* Db     = (bf16*)w; w += 3072;
    bf16* b1b    = (bf16*)w; w += 12288;
    bf16* b2b    = (bf16*)w; w += 3072;
    bf16* bnsb   = (bf16*)w; w += 3072;
    bf16* bnbb   = (bf16*)w; w += 3072;
    bf16* Woutb  = (bf16*)w; w += 5120;
    bf16* boutb  = (bf16*)w; w += 32;
    bf16* xb = bu;  // x's bf16 copy aliases bu (dead until first Bu GEMM)

    dim3 blk(256);
    detect_k<<<1, blk, 0, stream>>>((const unsigned short*)x, flag);
    cvt_k<<<16384, blk, 0, stream>>>(x, xb, 4194304, flag);
    cvt_k<<<1, blk, 0, stream>>>(b_enc, b_encb, 256, flag);
    cvt_k<<<6, blk, 0, stream>>>(Dp, Db, 1536, flag);
    cvt_k<<<24, blk, 0, stream>>>(b1, b1b, 6144, flag);
    cvt_k<<<6, blk, 0, stream>>>(b2, b2b, 1536, flag);
    cvt_k<<<6, blk, 0, stream>>>(bn_s, bnsb, 1536, flag);
    cvt_k<<<6, blk, 0, stream>>>(bn_b, bnbb, 1536, flag);
    cvt_k<<<10, blk, 0, stream>>>(W_out, Woutb, 2560, flag);
    cvt_k<<<1, blk, 0, stream>>>(b_out, boutb, 10, flag);
    lamgam_k<<<6, blk, 0, stream>>>(nu_log, th_log, lamb, gamt, flag);
    pack_wt_enc<<<64, blk, 0, stream>>>(W_enc, wt_enc, flag);

    // encoder: [M,64] @ W_enc^T + b_enc -> xc and y
    gemm_bt<1><<<dim3(512, 2), blk, 0, stream>>>(xb, 64, wt_enc, 64, xc, y, 256,
                                                 b_encb, nullptr, nullptr);
    for (int i = 0; i < 6; ++i) {
        bn_part<<<512, blk, 0, stream>>>(xc, bnpart);
        bn_finish<<<1, blk, 0, stream>>>(bnpart, stats);
        bn_apply<<<16384, blk, 0, stream>>>(xc, stats, bnsb + i * 256, bnbb + i * 256, hbn);
        pack_wb<<<512, blk, 0, stream>>>(B_re, B_im, (size_t)i * 65536, gamt + i * 256, wb, flag);
        // Bu = hbn @ (gamma*[B_re;B_im])^T -> [M,512] bf16
        gemm_bt<0><<<dim3(512, 4), blk, 0, stream>>>(hbn, 256, wb, 256, bu, nullptr, 512,
                                                     nullptr, nullptr, nullptr);
        lru_carry<<<512, blk, 0, stream>>>(bu, lamb + i * 512, carry);
        lru_prefix<<<32, blk, 0, stream>>>(carry, pre, lamb + i * 512);
        lru_final<<<512, blk, 0, stream>>>(bu, pre, lamb + i * 512);
        pack_wc<<<512, blk, 0, stream>>>(C_re, C_im, (size_t)i * 65536, wc, flag);
        // lru_out = hs @ [C_re;-C_im]^T + D*hbn -> hbn in-place [M,256]
        gemm_bt<2><<<dim3(512, 2), blk, 0, stream>>>(bu, 512, wc, 512, hbn, nullptr, 256,
                                                     nullptr, Db + i * 256, hbn);
        pack_w1t<<<1024, blk, 0, stream>>>(W1, (size_t)i * 262144, w1t, flag);
        // gate = sigmoid(hbn @ W1[:,512:] + b1[512:]) -> bu [M,512]
        gemm_bt<3><<<dim3(512, 4), blk, 0, stream>>>(hbn, 256, w1t + 131072, 256, bu, nullptr, 512,
                                                     b1b + i * 1024 + 512, nullptr, nullptr);
        // glu = (hbn @ W1[:,:512] + b1[:512]) * gate -> bu in-place [M,512]
        gemm_bt<4><<<dim3(512, 4), blk, 0, stream>>>(hbn, 256, w1t, 256, bu, nullptr, 512,
                                                     b1b + i * 1024, nullptr, bu);
        pack_w2t<<<512, blk, 0, stream>>>(W2, (size_t)i * 131072, w2t, flag);
        // xc = glu @ W2^T + b2 + y -> bf16
        gemm_bt<5><<<dim3(512, 2), blk, 0, stream>>>(bu, 512, w2t, 512, xc, nullptr, 256,
                                                     b2b + i * 256, nullptr, y);
    }
    pool_part<<<512, blk, 0, stream>>>(xc, part);
    head_k<<<32, blk, 0, stream>>>(part, Woutb, boutb, d_out, flag);
}